// Round 1
// 470.575 us; speedup vs baseline: 1.0620x; 1.0620x over previous
//
#include <hip/hip_runtime.h>

// R1: merge coherence+structure (role-interleaved blocks) for HBM/MFMA overlap;
//     coherence: dbuf 1-barrier k-loop + inverse-swizzled glds16 sources -> conflict-free ds_read_b128;
//     structure: XOR-swizzled Bs write/read (8-way -> free), T14 predT prefetch, nt adj loads.
// Predicted: dur_us 500 -> ~300; SQ_LDS_BANK_CONFLICT down >=5x on main kernel.

#define AS1 __attribute__((address_space(1)))
#define AS3 __attribute__((address_space(3)))

typedef __attribute__((ext_vector_type(8))) __bf16 bf16x8;
typedef __attribute__((ext_vector_type(8))) unsigned short ushort8;
typedef __attribute__((ext_vector_type(4))) float f32x4;

static constexpr int N  = 8192;
static constexpr int P  = 128;
static constexpr int D  = 256;
static constexpr int KC = 384;   // P + D concatenated K

__device__ __forceinline__ unsigned short f32_bf16(float f) {
  union { float f; unsigned u; } v; v.f = f;
  unsigned r = v.u + 0x7fffu + ((v.u >> 16) & 1u);   // round-to-nearest-even
  return (unsigned short)(r >> 16);
}

__device__ __forceinline__ void glds16(const void* g, void* l) {
  __builtin_amdgcn_global_load_lds((const AS1 void*)g, (AS3 void*)l, 16, 0, 0);
}

// ---------- P1: row-normalize embeddings -> xn into a_cat, -xn into b_cat ----------
__global__ __launch_bounds__(256)
void prep_xn_kernel(const float* __restrict__ emb,
                    unsigned short* __restrict__ a_cat,
                    unsigned short* __restrict__ b_cat) {
  const int i = blockIdx.x;
  const int j = threadIdx.x;            // D == 256 == blockDim
  float x = emb[(size_t)i * D + j];
  float ss = x * x;
  #pragma unroll
  for (int o = 32; o > 0; o >>= 1) ss += __shfl_down(ss, o, 64);
  __shared__ float red[4];
  if ((threadIdx.x & 63) == 0) red[threadIdx.x >> 6] = ss;
  __syncthreads();
  float tot = red[0] + red[1] + red[2] + red[3];
  float inv = 1.0f / fmaxf(sqrtf(tot), 1e-8f);
  float xn = x * inv;
  a_cat[(size_t)i * KC + P + j] = f32_bf16(xn);
  b_cat[(size_t)i * KC + P + j] = f32_bf16(-xn);
}

// ---------- P2: cast Pred -> cat arrays + LDS-tiled transpose predT + weight loss ----------
__global__ __launch_bounds__(256)
void prep_pred_kernel(const float* __restrict__ pred,
                      const float* __restrict__ wts,
                      unsigned short* __restrict__ a_cat,
                      unsigned short* __restrict__ b_cat,
                      unsigned short* __restrict__ predT,
                      float* __restrict__ wtp) {
  __shared__ unsigned short t[P][72];   // 64 i-cols + pad
  const int tid = threadIdx.x;
  const int i0 = blockIdx.x * 64;
  float s = 0.f;
  #pragma unroll
  for (int k = 0; k < 32; ++k) {
    int e = k * 256 + tid;              // 0..8191 over 64x128 tile
    int ii = e >> 7, p = e & 127;
    size_t idx = (size_t)(i0 + ii) * P + p;
    float v = pred[idx];
    unsigned short h = f32_bf16(v);
    a_cat[(size_t)(i0 + ii) * KC + p] = h;
    b_cat[(size_t)(i0 + ii) * KC + p] = h;
    t[p][ii] = h;
    float d = v - wts[idx];
    s += d * d;
  }
  __syncthreads();
  #pragma unroll
  for (int k = 0; k < 32; ++k) {
    int e = k * 256 + tid;
    int p = e >> 6, ii = e & 63;
    predT[(size_t)p * N + i0 + ii] = t[p][ii];   // coalesced 128B runs
  }
  #pragma unroll
  for (int o = 32; o > 0; o >>= 1) s += __shfl_down(s, o, 64);
  __shared__ float red[4];
  if ((tid & 63) == 0) red[tid >> 6] = s;
  __syncthreads();
  if (tid == 0) wtp[blockIdx.x] = red[0] + red[1] + red[2] + red[3];
}

// ---------- merged main kernel: role-split blocks ----------
// bid < 1536: bid%3==0 -> structure block (512 total); else coherence (1024)
// bid >= 1536: coherence (32)  => 1056 coherence + 512 structure = 1568 blocks.
// LDS union 64 KB -> 2 blocks/CU; HBM-bound structure overlaps MFMA-bound coherence.
__global__ __launch_bounds__(256, 2)
void main_kernel(const unsigned short* __restrict__ A,    // a_cat [pred | xn]
                 const unsigned short* __restrict__ Bm,   // b_cat [pred | -xn]
                 const float* __restrict__ adj,
                 const unsigned short* __restrict__ predT,
                 float* __restrict__ cohp,
                 float* __restrict__ cpart) {
  __shared__ unsigned short smem[32768];   // 64 KB, carved per role
  const int bid = blockIdx.x;
  const int tid = threadIdx.x;
  const int w = tid >> 6, lane = tid & 63;
  const int ml = lane & 15, kq = (lane >> 4) * 8;

  int role, idx;
  if (bid < 1536) {
    int q = bid / 3, r = bid - q * 3;
    if (r == 0) { role = 0; idx = q; }
    else        { role = 1; idx = q * 2 + (r - 1); }
  } else { role = 1; idx = 1024 + (bid - 1536); }

  if (role == 0) {
    // ===== structure: C[rows, P] = adj @ pred over k-slice; fp32 partial to cpart =====
    const int rb = idx & 127, slice = idx >> 7;
    const int row0 = rb * 64 + w * 16;
    unsigned short* Bs = smem;             // [8 chunks][128 p][32 k] bf16, XOR-swizzled
    f32x4 acc[8] = {};
    ushort8 stg[16];
    {
      const int kb0 = slice * 256;         // prologue: stage round 0
      #pragma unroll
      for (int i = 0; i < 16; ++i) {
        int e = i * 256 + tid;
        int p = e >> 5, kg = e & 31;
        stg[i] = *(const ushort8*)(predT + (size_t)p * N + kb0 + kg * 8);
      }
      #pragma unroll
      for (int i = 0; i < 16; ++i) {
        int e = i * 256 + tid;
        int p = e >> 5, kg = e & 31;
        int c = kg >> 2, kk = (kg & 3) * 8;
        int di = c * 4096 + p * 32 + kk;
        di ^= (((di >> 5) ^ (di >> 12)) & 7) << 3;   // spread p-write & ml-read to 8 quads
        *(ushort8*)&Bs[di] = stg[i];
      }
    }
    __syncthreads();
    for (int r = 0; r < 8; ++r) {
      const int kbase = (r * 4 + slice) * 256;
      if (r < 7) {                         // T14: issue next round's predT loads early
        const int kbn = kbase + 1024;
        #pragma unroll
        for (int i = 0; i < 16; ++i) {
          int e = i * 256 + tid;
          int p = e >> 5, kg = e & 31;
          stg[i] = *(const ushort8*)(predT + (size_t)p * N + kbn + kg * 8);
        }
      }
      const float* ab = adj + (size_t)(row0 + ml) * N + kbase + kq;
      f32x4 ring[3][2];
      #pragma unroll
      for (int s = 0; s < 3; ++s) {        // nt: don't evict coherence's L2 set
        ring[s][0] = __builtin_nontemporal_load((const f32x4*)(ab + s * 32));
        ring[s][1] = __builtin_nontemporal_load((const f32x4*)(ab + s * 32 + 4));
      }
      #pragma unroll
      for (int c = 0; c < 8; ++c) {
        f32x4 a0 = ring[c % 3][0], a1 = ring[c % 3][1];
        if (c < 5) {
          ring[c % 3][0] = __builtin_nontemporal_load((const f32x4*)(ab + (c + 3) * 32));
          ring[c % 3][1] = __builtin_nontemporal_load((const f32x4*)(ab + (c + 3) * 32 + 4));
        }
        union { bf16x8 v; unsigned short h[8]; } ah;
        ah.h[0] = f32_bf16(a0[0]); ah.h[1] = f32_bf16(a0[1]);
        ah.h[2] = f32_bf16(a0[2]); ah.h[3] = f32_bf16(a0[3]);
        ah.h[4] = f32_bf16(a1[0]); ah.h[5] = f32_bf16(a1[1]);
        ah.h[6] = f32_bf16(a1[2]); ah.h[7] = f32_bf16(a1[3]);
        #pragma unroll
        for (int f = 0; f < 8; ++f) {
          int bix = c * 4096 + (f * 16 + ml) * 32 + kq;
          bix ^= (((bix >> 5) ^ (bix >> 12)) & 7) << 3;
          bf16x8 bv = *(const bf16x8*)&Bs[bix];
          acc[f] = __builtin_amdgcn_mfma_f32_16x16x32_bf16(ah.v, bv, acc[f], 0, 0, 0);
        }
      }
      __syncthreads();                     // all waves done reading Bs (drains vmcnt too)
      if (r < 7) {
        #pragma unroll
        for (int i = 0; i < 16; ++i) {
          int e = i * 256 + tid;
          int p = e >> 5, kg = e & 31;
          int c = kg >> 2, kk = (kg & 3) * 8;
          int di = c * 4096 + p * 32 + kk;
          di ^= (((di >> 5) ^ (di >> 12)) & 7) << 3;
          *(ushort8*)&Bs[di] = stg[i];
        }
        __syncthreads();
      }
    }
    float* cp = cpart + (size_t)slice * ((size_t)N * P);
    const int rbs = row0 + (lane >> 4) * 4;
    #pragma unroll
    for (int f = 0; f < 8; ++f)
      #pragma unroll
      for (int e = 0; e < 4; ++e)
        __builtin_nontemporal_store(acc[f][e], &cp[(size_t)(rbs + e) * P + f * 16 + ml]);
  } else {
    // ===== coherence: 128x256 tile of (A·Bm^T), triangular weights, squared-sum =====
    const int t = idx;                     // 0..1055; offset(bj) = bj^2 + bj
    int bj = (int)((sqrtf(4.0f * (float)t + 1.0f) - 1.0f) * 0.5f);
    while ((bj + 1) * (bj + 2) <= t) ++bj;
    while (bj * bj + bj > t) --bj;
    const int bi = t - bj * bj - bj;
    const int wr = (w & 1) * 64, wc = (w >> 1) * 128;
    f32x4 acc[4][8] = {};
    const size_t abase = (size_t)bi * 128 * KC;
    const size_t bbase = (size_t)bj * 256 * KC;
    // inverse-swizzle glds16 source offsets: LDS slot e (linear DMA dest) <- (row,col)
    // such that read addr (row*32+kq) ^ ((row&7)<<3) finds element (row, kq).
    int off[4];
    #pragma unroll
    for (int p = 0; p < 4; ++p) {
      int e = p * 2048 + tid * 8;
      int r2 = (e >> 7) & 1, r1 = (e >> 6) & 1;
      int r0 = ((e >> 5) & 1) ^ r2;
      int row = ((e >> 8) << 3) | (r2 << 2) | (r1 << 1) | r0;
      int col = ((((e >> 3) & 1) ^ r0) << 3) | ((((e >> 4) & 1) ^ r1) << 4);
      off[p] = row * KC + col;
    }
    const int swz = (ml * 32 + kq) ^ ((ml & 7) << 3);   // per-lane conflict-free read offset
    auto stage = [&](int buf, int k0) {
      #pragma unroll
      for (int p = 0; p < 2; ++p)        // As half: 8 KB
        glds16(A + abase + off[p] + k0, &smem[buf * 4096 + p * 2048 + tid * 8]);
      #pragma unroll
      for (int p = 0; p < 4; ++p)        // Bs half: 16 KB
        glds16(Bm + bbase + off[p] + k0, &smem[8192 + buf * 8192 + p * 2048 + tid * 8]);
    };
    stage(0, 0);
    __syncthreads();                     // buf0 ready (vmcnt drained by barrier)
    #pragma unroll
    for (int step = 0; step < 12; ++step) {
      const int cur = step & 1;
      if (step < 11) stage(cur ^ 1, (step + 1) * 32);   // prefetch overlaps MFMA
      bf16x8 af[4], bf[8];
      #pragma unroll
      for (int a = 0; a < 4; ++a)
        af[a] = *(const bf16x8*)&smem[cur * 4096 + (wr + a * 16) * 32 + swz];
      #pragma unroll
      for (int f = 0; f < 8; ++f)
        bf[f] = *(const bf16x8*)&smem[8192 + cur * 8192 + (wc + f * 16) * 32 + swz];
      __builtin_amdgcn_s_setprio(1);
      #pragma unroll
      for (int a = 0; a < 4; ++a)
        #pragma unroll
        for (int f = 0; f < 8; ++f)
          acc[a][f] = __builtin_amdgcn_mfma_f32_16x16x32_bf16(af[a], bf[f], acc[a][f], 0, 0, 0);
      __builtin_amdgcn_s_setprio(0);
      __syncthreads();                   // reads of buf[cur] retired; next stage may overwrite
    }
    // C/D: col=lane&15 (B/j index), row=(lane>>4)*4+e (A/i index)
    float s = 0.f;
    const int ib = bi * 128 + wr + (lane >> 4) * 4;
    const int jb = bj * 256 + wc + ml;
    #pragma unroll
    for (int a = 0; a < 4; ++a)
      #pragma unroll
      for (int f = 0; f < 8; ++f)
        #pragma unroll
        for (int e = 0; e < 4; ++e) {
          int i = ib + a * 16 + e, j = jb + f * 16;
          float wgt = (i < j) ? 2.f : ((i == j) ? 1.f : 0.f);
          float c = acc[a][f][e];
          s += wgt * c * c;
        }
    #pragma unroll
    for (int o = 32; o > 0; o >>= 1) s += __shfl_down(s, o, 64);
    float* red = (float*)&smem[28672];   // beyond coherence's 24576-ushort use
    if (lane == 0) red[w] = s;
    __syncthreads();
    if (tid == 0) cohp[t] = red[0] + red[1] + red[2] + red[3];
  }
}

// ---------- structure reduce: sum 4 fp32 partial slices, (pred - C)^2 ----------
__global__ __launch_bounds__(256)
void structure_reduce_kernel(const float* __restrict__ cpart,
                             const float* __restrict__ pred,
                             float* __restrict__ strp) {
  const int tid = threadIdx.x;
  const size_t base = ((size_t)blockIdx.x * 256 + tid) * 8;
  const float4 p0 = *(const float4*)(pred + base);
  const float4 p1 = *(const float4*)(pred + base + 4);
  float c[8] = {};
  #pragma unroll
  for (int sl = 0; sl < 4; ++sl) {
    float4 c0 = *(const float4*)(cpart + (size_t)sl * ((size_t)N * P) + base);
    float4 c1 = *(const float4*)(cpart + (size_t)sl * ((size_t)N * P) + base + 4);
    c[0] += c0.x; c[1] += c0.y; c[2] += c0.z; c[3] += c0.w;
    c[4] += c1.x; c[5] += c1.y; c[6] += c1.z; c[7] += c1.w;
  }
  const float pv[8] = {p0.x, p0.y, p0.z, p0.w, p1.x, p1.y, p1.z, p1.w};
  float s = 0.f;
  #pragma unroll
  for (int e = 0; e < 8; ++e) { float d = pv[e] - c[e]; s += d * d; }
  #pragma unroll
  for (int o = 32; o > 0; o >>= 1) s += __shfl_down(s, o, 64);
  __shared__ float red[4];
  if ((tid & 63) == 0) red[tid >> 6] = s;
  __syncthreads();
  if (tid == 0) strp[blockIdx.x] = red[0] + red[1] + red[2] + red[3];
}

// ---------- final: fp64 reduce of partials, combine losses ----------
__global__ __launch_bounds__(256)
void finalize_kernel(const float* __restrict__ cohp,
                     const float* __restrict__ wtp,
                     const float* __restrict__ strp,
                     float* __restrict__ out) {
  const int tid = threadIdx.x;
  double sc = 0, sw = 0, ss = 0;
  for (int i = tid; i < 1056; i += 256) sc += (double)cohp[i];
  for (int i = tid; i < 128;  i += 256) sw += (double)wtp[i];
  for (int i = tid; i < 512;  i += 256) ss += (double)strp[i];
  #pragma unroll
  for (int o = 32; o > 0; o >>= 1) {
    sc += __shfl_down(sc, o, 64);
    sw += __shfl_down(sw, o, 64);
    ss += __shfl_down(ss, o, 64);
  }
  __shared__ double rd[3][4];
  const int w = tid >> 6, lane = tid & 63;
  if (lane == 0) { rd[0][w] = sc; rd[1][w] = sw; rd[2][w] = ss; }
  __syncthreads();
  if (tid == 0) {
    double c  = rd[0][0] + rd[0][1] + rd[0][2] + rd[0][3];
    double wv = rd[1][0] + rd[1][1] + rd[1][2] + rd[1][3];
    double st = rd[2][0] + rd[2][1] + rd[2][2] + rd[2][3];
    out[0] = (float)(c / ((double)N * (double)N) +
                     st / ((double)N * (double)P) +
                     wv / ((double)N * (double)P));
  }
}

extern "C" void kernel_launch(void* const* d_in, const int* in_sizes, int n_in,
                              void* d_out, int out_size, void* d_ws, size_t ws_size,
                              hipStream_t stream) {
  const float* pred = (const float*)d_in[0];   // [8192,128]
  const float* emb  = (const float*)d_in[1];   // [8192,256]
  const float* adj  = (const float*)d_in[2];   // [8192,8192]
  const float* wts  = (const float*)d_in[3];   // [8192,128]
  float* out = (float*)d_out;
  char* ws = (char*)d_ws;
  // ws (~31.5 MB): no overlay now — coherence & structure run CONCURRENTLY in main_kernel,
  // so a_cat/b_cat stay live alongside cpart.
  unsigned short* a_cat = (unsigned short*)ws;               // [8192,384] bf16 = 6.29 MB
  unsigned short* b_cat = (unsigned short*)(ws + 6291456);   // [8192,384] bf16 = 6.29 MB
  unsigned short* predT = (unsigned short*)(ws + 12582912);  // [128,8192] bf16 = 2 MB
  float*          cpart = (float*)(ws + 14680064);           // 4 x [8192,128] fp32 = 16 MB
  float* cohp = (float*)(ws + 31457280);                     // 1056
  float* wtp  = cohp + 1056;                                 // 128
  float* strp = wtp + 128;                                   // 512

  prep_xn_kernel  <<<N,      256, 0, stream>>>(emb, a_cat, b_cat);
  prep_pred_kernel<<<N / 64, 256, 0, stream>>>(pred, wts, a_cat, b_cat, predT, wtp);
  main_kernel     <<<1568,   256, 0, stream>>>(a_cat, b_cat, adj, predT, cohp, cpart);
  structure_reduce_kernel<<<512, 256, 0, stream>>>(cpart, pred, strp);
  finalize_kernel <<<1,      256, 0, stream>>>(cohp, wtp, strp, out);
}

// Round 3
// 467.304 us; speedup vs baseline: 1.0695x; 1.0070x over previous
//
#include <hip/hip_runtime.h>

// R3: resubmit of R2 (container infra failure, not a kernel fault). One defensive change:
//     explicit ushort8 sign-mask constant instead of vector^=scalar broadcast.
//     R2 content: kill b_cat (f32_bf16(-x) == f32_bf16(x)^0x8000 bit-exact, flip in-register);
//     merged vectorized prep; structure path unchanged.
// Predicted: dur_us 470 -> ~455. If delta <= ~5us, harness reset floor dominates -> roofline.

#define AS1 __attribute__((address_space(1)))
#define AS3 __attribute__((address_space(3)))

typedef __attribute__((ext_vector_type(8))) __bf16 bf16x8;
typedef __attribute__((ext_vector_type(8))) unsigned short ushort8;
typedef __attribute__((ext_vector_type(4))) float f32x4;

static constexpr int N  = 8192;
static constexpr int P  = 128;
static constexpr int D  = 256;
static constexpr int KC = 384;   // P + D concatenated K

__device__ __forceinline__ unsigned short f32_bf16(float f) {
  union { float f; unsigned u; } v; v.f = f;
  unsigned r = v.u + 0x7fffu + ((v.u >> 16) & 1u);   // round-to-nearest-even
  return (unsigned short)(r >> 16);
}

__device__ __forceinline__ void glds16(const void* g, void* l) {
  __builtin_amdgcn_global_load_lds((const AS1 void*)g, (AS3 void*)l, 16, 0, 0);
}

// ---------- merged prep: blocks [0,2048) xn role, [2048,2176) pred role ----------
__global__ __launch_bounds__(256)
void prep_all_kernel(const float* __restrict__ emb,
                     const float* __restrict__ pred,
                     const float* __restrict__ wts,
                     unsigned short* __restrict__ a_cat,
                     unsigned short* __restrict__ predT,
                     float* __restrict__ wtp) {
  __shared__ unsigned short t[P][72];   // pred role only
  __shared__ float red[4];              // pred role only
  const int tid = threadIdx.x;
  if (blockIdx.x < 2048) {
    // --- xn role: one wave per row, float4 loads, packed bf16x4 store ---
    const int w = tid >> 6, lane = tid & 63;
    const int row = (blockIdx.x << 2) | w;
    const float4 x = *(const float4*)(emb + (size_t)row * D + lane * 4);
    float ss = x.x * x.x + x.y * x.y + x.z * x.z + x.w * x.w;
    #pragma unroll
    for (int o = 32; o > 0; o >>= 1) ss += __shfl_down(ss, o, 64);
    const float tot = __shfl(ss, 0, 64);
    const float inv = 1.0f / fmaxf(sqrtf(tot), 1e-8f);
    ushort4 h;
    h.x = f32_bf16(x.x * inv); h.y = f32_bf16(x.y * inv);
    h.z = f32_bf16(x.z * inv); h.w = f32_bf16(x.w * inv);
    *(ushort4*)(a_cat + (size_t)row * KC + P + lane * 4) = h;
  } else {
    // --- pred role: cast pred -> a_cat + LDS-tiled transpose predT + weight loss ---
    const int idx = blockIdx.x - 2048;           // 0..127
    const int i0 = idx * 64;
    float s = 0.f;
    #pragma unroll
    for (int k = 0; k < 32; ++k) {
      int e = k * 256 + tid;              // 0..8191 over 64x128 tile
      int ii = e >> 7, p = e & 127;
      size_t gi = (size_t)(i0 + ii) * P + p;
      float v = pred[gi];
      unsigned short h = f32_bf16(v);
      a_cat[(size_t)(i0 + ii) * KC + p] = h;
      t[p][ii] = h;
      float d = v - wts[gi];
      s += d * d;
    }
    __syncthreads();
    #pragma unroll
    for (int k = 0; k < 32; ++k) {
      int e = k * 256 + tid;
      int p = e >> 6, ii = e & 63;
      predT[(size_t)p * N + i0 + ii] = t[p][ii];   // coalesced 128B runs
    }
    #pragma unroll
    for (int o = 32; o > 0; o >>= 1) s += __shfl_down(s, o, 64);
    if ((tid & 63) == 0) red[tid >> 6] = s;
    __syncthreads();
    if (tid == 0) wtp[idx] = red[0] + red[1] + red[2] + red[3];
  }
}

// ---------- merged main kernel: role-split blocks ----------
// bid < 1536: bid%3==0 -> structure block (512 total); else coherence (1024)
// bid >= 1536: coherence (32)  => 1056 coherence + 512 structure = 1568 blocks.
__global__ __launch_bounds__(256, 2)
void main_kernel(const unsigned short* __restrict__ A,    // a_cat [pred | xn]
                 const float* __restrict__ adj,
                 const unsigned short* __restrict__ predT,
                 float* __restrict__ cohp,
                 float* __restrict__ cpart) {
  __shared__ unsigned short smem[32768];   // 64 KB, carved per role
  const int bid = blockIdx.x;
  const int tid = threadIdx.x;
  const int w = tid >> 6, lane = tid & 63;
  const int ml = lane & 15, kq = (lane >> 4) * 8;

  int role, idx;
  if (bid < 1536) {
    int q = bid / 3, r = bid - q * 3;
    if (r == 0) { role = 0; idx = q; }
    else        { role = 1; idx = q * 2 + (r - 1); }
  } else { role = 1; idx = 1024 + (bid - 1536); }

  if (role == 0) {
    // ===== structure: C[rows, P] = adj @ pred over k-slice; fp32 partial to cpart =====
    const int rb = idx & 127, slice = idx >> 7;
    const int row0 = rb * 64 + w * 16;
    unsigned short* Bs = smem;             // [8 chunks][128 p][32 k] bf16, XOR-swizzled
    f32x4 acc[8] = {};
    ushort8 stg[16];
    {
      const int kb0 = slice * 256;         // prologue: stage round 0
      #pragma unroll
      for (int i = 0; i < 16; ++i) {
        int e = i * 256 + tid;
        int p = e >> 5, kg = e & 31;
        stg[i] = *(const ushort8*)(predT + (size_t)p * N + kb0 + kg * 8);
      }
      #pragma unroll
      for (int i = 0; i < 16; ++i) {
        int e = i * 256 + tid;
        int p = e >> 5, kg = e & 31;
        int c = kg >> 2, kk = (kg & 3) * 8;
        int di = c * 4096 + p * 32 + kk;
        di ^= (((di >> 5) ^ (di >> 12)) & 7) << 3;   // spread p-write & ml-read to 8 quads
        *(ushort8*)&Bs[di] = stg[i];
      }
    }
    __syncthreads();
    for (int r = 0; r < 8; ++r) {
      const int kbase = (r * 4 + slice) * 256;
      if (r < 7) {                         // T14: issue next round's predT loads early
        const int kbn = kbase + 1024;
        #pragma unroll
        for (int i = 0; i < 16; ++i) {
          int e = i * 256 + tid;
          int p = e >> 5, kg = e & 31;
          stg[i] = *(const ushort8*)(predT + (size_t)p * N + kbn + kg * 8);
        }
      }
      const float* ab = adj + (size_t)(row0 + ml) * N + kbase + kq;
      f32x4 ring[3][2];
      #pragma unroll
      for (int s = 0; s < 3; ++s) {        // nt: don't evict coherence's L2 set
        ring[s][0] = __builtin_nontemporal_load((const f32x4*)(ab + s * 32));
        ring[s][1] = __builtin_nontemporal_load((const f32x4*)(ab + s * 32 + 4));
      }
      #pragma unroll
      for (int c = 0; c < 8; ++c) {
        f32x4 a0 = ring[c % 3][0], a1 = ring[c % 3][1];
        if (c < 5) {
          ring[c % 3][0] = __builtin_nontemporal_load((const f32x4*)(ab + (c + 3) * 32));
          ring[c % 3][1] = __builtin_nontemporal_load((const f32x4*)(ab + (c + 3) * 32 + 4));
        }
        union { bf16x8 v; unsigned short h[8]; } ah;
        ah.h[0] = f32_bf16(a0[0]); ah.h[1] = f32_bf16(a0[1]);
        ah.h[2] = f32_bf16(a0[2]); ah.h[3] = f32_bf16(a0[3]);
        ah.h[4] = f32_bf16(a1[0]); ah.h[5] = f32_bf16(a1[1]);
        ah.h[6] = f32_bf16(a1[2]); ah.h[7] = f32_bf16(a1[3]);
        #pragma unroll
        for (int f = 0; f < 8; ++f) {
          int bix = c * 4096 + (f * 16 + ml) * 32 + kq;
          bix ^= (((bix >> 5) ^ (bix >> 12)) & 7) << 3;
          bf16x8 bv = *(const bf16x8*)&Bs[bix];
          acc[f] = __builtin_amdgcn_mfma_f32_16x16x32_bf16(ah.v, bv, acc[f], 0, 0, 0);
        }
      }
      __syncthreads();                     // all waves done reading Bs (drains vmcnt too)
      if (r < 7) {
        #pragma unroll
        for (int i = 0; i < 16; ++i) {
          int e = i * 256 + tid;
          int p = e >> 5, kg = e & 31;
          int c = kg >> 2, kk = (kg & 3) * 8;
          int di = c * 4096 + p * 32 + kk;
          di ^= (((di >> 5) ^ (di >> 12)) & 7) << 3;
          *(ushort8*)&Bs[di] = stg[i];
        }
        __syncthreads();
      }
    }
    float* cp = cpart + (size_t)slice * ((size_t)N * P);
    const int rbs = row0 + (lane >> 4) * 4;
    #pragma unroll
    for (int f = 0; f < 8; ++f)
      #pragma unroll
      for (int e = 0; e < 4; ++e)
        __builtin_nontemporal_store(acc[f][e], &cp[(size_t)(rbs + e) * P + f * 16 + ml]);
  } else {
    // ===== coherence: 128x256 tile of (A . A^T with xn sign-flip), triangular weights =====
    const int t = idx;                     // 0..1055; offset(bj) = bj^2 + bj
    int bj = (int)((sqrtf(4.0f * (float)t + 1.0f) - 1.0f) * 0.5f);
    while ((bj + 1) * (bj + 2) <= t) ++bj;
    while (bj * bj + bj > t) --bj;
    const int bi = t - bj * bj - bj;
    const int wr = (w & 1) * 64, wc = (w >> 1) * 128;
    f32x4 acc[4][8] = {};
    const size_t abase = (size_t)bi * 128 * KC;
    const size_t bbase = (size_t)bj * 256 * KC;
    // inverse-swizzle glds16 source offsets: LDS slot e (linear DMA dest) <- (row,col)
    // such that read addr (row*32+kq) ^ ((row&7)<<3) finds element (row, kq).
    int off[4];
    #pragma unroll
    for (int p = 0; p < 4; ++p) {
      int e = p * 2048 + tid * 8;
      int r2 = (e >> 7) & 1, r1 = (e >> 6) & 1;
      int r0 = ((e >> 5) & 1) ^ r2;
      int row = ((e >> 8) << 3) | (r2 << 2) | (r1 << 1) | r0;
      int col = ((((e >> 3) & 1) ^ r0) << 3) | ((((e >> 4) & 1) ^ r1) << 4);
      off[p] = row * KC + col;
    }
    const int swz = (ml * 32 + kq) ^ ((ml & 7) << 3);   // per-lane conflict-free read offset
    auto stage = [&](int buf, int k0) {
      #pragma unroll
      for (int p = 0; p < 2; ++p)        // As half: 8 KB (a_cat, rows bi*128..)
        glds16(A + abase + off[p] + k0, &smem[buf * 4096 + p * 2048 + tid * 8]);
      #pragma unroll
      for (int p = 0; p < 4; ++p)        // Bs half: 16 KB (a_cat, rows bj*256..)
        glds16(A + bbase + off[p] + k0, &smem[8192 + buf * 8192 + p * 2048 + tid * 8]);
    };
    stage(0, 0);
    __syncthreads();                     // buf0 ready (vmcnt drained by barrier)
    const ushort8 smask = {0x8000u, 0x8000u, 0x8000u, 0x8000u,
                           0x8000u, 0x8000u, 0x8000u, 0x8000u};
    #pragma unroll
    for (int step = 0; step < 12; ++step) {
      const int cur = step & 1;
      if (step < 11) stage(cur ^ 1, (step + 1) * 32);   // prefetch overlaps MFMA
      bf16x8 af[4], bf[8];
      #pragma unroll
      for (int a = 0; a < 4; ++a)
        af[a] = *(const bf16x8*)&smem[cur * 4096 + (wr + a * 16) * 32 + swz];
      #pragma unroll
      for (int f = 0; f < 8; ++f) {
        ushort8 u = *(const ushort8*)&smem[8192 + cur * 8192 + (wc + f * 16) * 32 + swz];
        if (step >= 4) u ^= smask;       // -xn half: bit-exact vs f32_bf16(-x)
        union { ushort8 u; bf16x8 v; } cv; cv.u = u;
        bf[f] = cv.v;
      }
      __builtin_amdgcn_s_setprio(1);
      #pragma unroll
      for (int a = 0; a < 4; ++a)
        #pragma unroll
        for (int f = 0; f < 8; ++f)
          acc[a][f] = __builtin_amdgcn_mfma_f32_16x16x32_bf16(af[a], bf[f], acc[a][f], 0, 0, 0);
      __builtin_amdgcn_s_setprio(0);
      __syncthreads();                   // reads of buf[cur] retired; next stage may overwrite
    }
    // C/D: col=lane&15 (B/j index), row=(lane>>4)*4+e (A/i index)
    float s = 0.f;
    const int ib = bi * 128 + wr + (lane >> 4) * 4;
    const int jb = bj * 256 + wc + ml;
    #pragma unroll
    for (int a = 0; a < 4; ++a)
      #pragma unroll
      for (int f = 0; f < 8; ++f)
        #pragma unroll
        for (int e = 0; e < 4; ++e) {
          int i = ib + a * 16 + e, j = jb + f * 16;
          float wgt = (i < j) ? 2.f : ((i == j) ? 1.f : 0.f);
          float c = acc[a][f][e];
          s += wgt * c * c;
        }
    #pragma unroll
    for (int o = 32; o > 0; o >>= 1) s += __shfl_down(s, o, 64);
    float* red = (float*)&smem[28672];   // beyond coherence's 24576-ushort use
    if (lane == 0) red[w] = s;
    __syncthreads();
    if (tid == 0) cohp[t] = red[0] + red[1] + red[2] + red[3];
  }
}

// ---------- structure reduce: sum 4 fp32 partial slices, (pred - C)^2 ----------
__global__ __launch_bounds__(256)
void structure_reduce_kernel(const float* __restrict__ cpart,
                             const float* __restrict__ pred,
                             float* __restrict__ strp) {
  const int tid = threadIdx.x;
  const size_t base = ((size_t)blockIdx.x * 256 + tid) * 8;
  const float4 p0 = *(const float4*)(pred + base);
  const float4 p1 = *(const float4*)(pred + base + 4);
  float c[8] = {};
  #pragma unroll
  for (int sl = 0; sl < 4; ++sl) {
    float4 c0 = *(const float4*)(cpart + (size_t)sl * ((size_t)N * P) + base);
    float4 c1 = *(const float4*)(cpart + (size_t)sl * ((size_t)N * P) + base + 4);
    c[0] += c0.x; c[1] += c0.y; c[2] += c0.z; c[3] += c0.w;
    c[4] += c1.x; c[5] += c1.y; c[6] += c1.z; c[7] += c1.w;
  }
  const float pv[8] = {p0.x, p0.y, p0.z, p0.w, p1.x, p1.y, p1.z, p1.w};
  float s = 0.f;
  #pragma unroll
  for (int e = 0; e < 8; ++e) { float d = pv[e] - c[e]; s += d * d; }
  #pragma unroll
  for (int o = 32; o > 0; o >>= 1) s += __shfl_down(s, o, 64);
  __shared__ float red[4];
  if ((tid & 63) == 0) red[tid >> 6] = s;
  __syncthreads();
  if (tid == 0) strp[blockIdx.x] = red[0] + red[1] + red[2] + red[3];
}

// ---------- final: fp64 reduce of partials, combine losses ----------
__global__ __launch_bounds__(256)
void finalize_kernel(const float* __restrict__ cohp,
                     const float* __restrict__ wtp,
                     const float* __restrict__ strp,
                     float* __restrict__ out) {
  const int tid = threadIdx.x;
  double sc = 0, sw = 0, ss = 0;
  for (int i = tid; i < 1056; i += 256) sc += (double)cohp[i];
  for (int i = tid; i < 128;  i += 256) sw += (double)wtp[i];
  for (int i = tid; i < 512;  i += 256) ss += (double)strp[i];
  #pragma unroll
  for (int o = 32; o > 0; o >>= 1) {
    sc += __shfl_down(sc, o, 64);
    sw += __shfl_down(sw, o, 64);
    ss += __shfl_down(ss, o, 64);
  }
  __shared__ double rd[3][4];
  const int w = tid >> 6, lane = tid & 63;
  if (lane == 0) { rd[0][w] = sc; rd[1][w] = sw; rd[2][w] = ss; }
  __syncthreads();
  if (tid == 0) {
    double c  = rd[0][0] + rd[0][1] + rd[0][2] + rd[0][3];
    double wv = rd[1][0] + rd[1][1] + rd[1][2] + rd[1][3];
    double st = rd[2][0] + rd[2][1] + rd[2][2] + rd[2][3];
    out[0] = (float)(c / ((double)N * (double)N) +
                     st / ((double)N * (double)P) +
                     wv / ((double)N * (double)P));
  }
}

extern "C" void kernel_launch(void* const* d_in, const int* in_sizes, int n_in,
                              void* d_out, int out_size, void* d_ws, size_t ws_size,
                              hipStream_t stream) {
  const float* pred = (const float*)d_in[0];   // [8192,128]
  const float* emb  = (const float*)d_in[1];   // [8192,256]
  const float* adj  = (const float*)d_in[2];   // [8192,8192]
  const float* wts  = (const float*)d_in[3];   // [8192,128]
  float* out = (float*)d_out;
  char* ws = (char*)d_ws;
  // ws (~25.2 MB): a_cat 6.29 MB | predT 2 MB | cpart 16 MB | partials
  unsigned short* a_cat = (unsigned short*)ws;               // [8192,384] bf16 = 6.29 MB
  unsigned short* predT = (unsigned short*)(ws + 6291456);   // [128,8192] bf16 = 2 MB
  float*          cpart = (float*)(ws + 8388608);            // 4 x [8192,128] fp32 = 16 MB
  float* cohp = (float*)(ws + 25165824);                     // 1056
  float* wtp  = cohp + 1056;                                 // 128
  float* strp = wtp + 128;                                   // 512

  prep_all_kernel <<<2176,   256, 0, stream>>>(emb, pred, wts, a_cat, predT, wtp);
  main_kernel     <<<1568,   256, 0, stream>>>(a_cat, adj, predT, cohp, cpart);
  structure_reduce_kernel<<<512, 256, 0, stream>>>(cpart, pred, strp);
  finalize_kernel <<<1,      256, 0, stream>>>(cohp, wtp, strp, out);
}